// Round 14
// baseline (117.234 us; speedup 1.0000x reference)
//
#include <hip/hip_runtime.h>
#include <math.h>

#define NUM_TASKS 16
#define B_ROWS    8192
#define P_ROWS    8448             // sorted-row space, each task 16-aligned

typedef __attribute__((ext_vector_type(4))) float f32x4;
typedef __attribute__((ext_vector_type(8))) short bf16x8;
typedef __attribute__((ext_vector_type(4))) short bf16x4;
typedef unsigned short ushort_t;

__device__ __forceinline__ short f2bf(float f) {
    union { float f; unsigned u; } c; c.f = f;
    unsigned u = c.u;
    unsigned r = (u + 0x7FFFu + ((u >> 16) & 1u)) >> 16;
    return (short)r;
}

__device__ __forceinline__ float fast_tanh(float x) {
    float e = __expf(2.0f * x);
    return 1.0f - 2.0f / (e + 1.0f);
}

__device__ __forceinline__ void gld16(const void* g, void* l) {
    __builtin_amdgcn_global_load_lds(
        (const __attribute__((address_space(1))) unsigned int*)g,
        (__attribute__((address_space(3))) unsigned int*)l,
        16, 0, 0);
}

// ---------------------------------------------------------------------------
// Packed fragment-major layout ([X][K], 16-row groups), verified R12:
//   elem(x,k;K) = ((x>>4)*(K/8) + (k>>3))*128 + slot*8 + (k&7)
// H (x, H0, H1): slot = (x&15)                       [global, no swizzle]
// W:             slot = (n&15) ^ ((k>>3)&3)          [LDS bank swizzle]
// One frag (16 x-rows x 32 k) = 1 KB; lane l: 16B at (l>>4)*256 + slot(l)*16.
// ---------------------------------------------------------------------------

// ---------------------------------------------------------------------------
// Bucket: stable counting sort of rows by task; task starts 16-aligned.
// ---------------------------------------------------------------------------
__global__ __launch_bounds__(256) void bucket_kernel(
    const int* __restrict__ task_ids,
    int* __restrict__ sidx,
    int* __restrict__ pstart_g,
    int* __restrict__ tot_g)
{
    __shared__ int cnt[256][NUM_TASKS];
    __shared__ int pstart[NUM_TASKS];
    __shared__ int tot[NUM_TASKS];

    const int tid = threadIdx.x;
    #pragma unroll
    for (int t = 0; t < NUM_TASKS; ++t) cnt[tid][t] = 0;
    const int base = tid * (B_ROWS / 256);

    for (int i = 0; i < B_ROWS / 256; ++i) {
        int t = task_ids[base + i];
        cnt[tid][t]++;
    }
    __syncthreads();

    if (tid < NUM_TASKS) {
        int s = 0;
        for (int c = 0; c < 256; ++c) { int v = cnt[c][tid]; cnt[c][tid] = s; s += v; }
        tot[tid] = s;
    }
    __syncthreads();

    if (tid == 0) {
        int p = 0;
        for (int t = 0; t < NUM_TASKS; ++t) {
            pstart[t] = p;
            p += ((tot[t] + 15) / 16) * 16;
        }
    }
    __syncthreads();

    if (tid < NUM_TASKS) {
        pstart_g[tid] = pstart[tid];
        tot_g[tid]    = tot[tid];
    }

    for (int i = 0; i < P_ROWS / 256; ++i) sidx[tid + i * 256] = 0;
    __syncthreads();

    for (int i = 0; i < B_ROWS / 256; ++i) {
        int row = base + i;
        int t = task_ids[row];
        int pos = pstart[t] + cnt[tid][t];
        cnt[tid][t] = cnt[tid][t] + 1;
        sidx[pos] = row;
    }
}

// ---------------------------------------------------------------------------
// x gather + convert + pack (verified R12): xs = packed(x[sidx[pos]]), K=512.
// ---------------------------------------------------------------------------
__global__ __launch_bounds__(256) void xconv(
    const float* __restrict__ x,
    const int* __restrict__ sidx,
    ushort_t* __restrict__ xs)
{
    const int tid  = threadIdx.x;
    const int pos  = blockIdx.x * 4 + (tid >> 6);
    const int lane = tid & 63;
    const int src  = sidx[pos];
    const float* sp = x + (size_t)src * 512 + lane * 8;
    f32x4 v0 = *(const f32x4*)sp;
    f32x4 v1 = *(const f32x4*)(sp + 4);
    bf16x8 pk;
    pk[0] = f2bf(v0[0]); pk[1] = f2bf(v0[1]);
    pk[2] = f2bf(v0[2]); pk[3] = f2bf(v0[3]);
    pk[4] = f2bf(v1[0]); pk[5] = f2bf(v1[1]);
    pk[6] = f2bf(v1[2]); pk[7] = f2bf(v1[3]);
    ushort_t* dp = xs + ((size_t)(pos >> 4) * 64 + lane) * 128 + (pos & 15) * 8;
    *(bf16x8*)dp = pk;
}

// ---------------------------------------------------------------------------
// Weight convert + transpose + pack (R12 + kg&3 slot swizzle for LDS banks).
// ---------------------------------------------------------------------------
template<int K, int N>
__global__ __launch_bounds__(256) void wconv(
    const float* __restrict__ W, ushort_t* __restrict__ Wt)
{
    const int t  = blockIdx.z;
    const int kb = blockIdx.y * 64;
    const int nb = blockIdx.x * 64;
    const float* src = W + (size_t)t * K * N;
    ushort_t* dst = Wt + (size_t)t * N * K;

    __shared__ ushort_t tile[64][68];

    const int tid = threadIdx.x;
    {
        int kl  = tid >> 4;
        int nl4 = (tid & 15) * 4;
        #pragma unroll
        for (int r = 0; r < 4; ++r) {
            int k = kl + r * 16;
            f32x4 v = *(const f32x4*)(src + (size_t)(kb + k) * N + nb + nl4);
            tile[nl4 + 0][k] = (ushort_t)f2bf(v[0]);
            tile[nl4 + 1][k] = (ushort_t)f2bf(v[1]);
            tile[nl4 + 2][k] = (ushort_t)f2bf(v[2]);
            tile[nl4 + 3][k] = (ushort_t)f2bf(v[3]);
        }
    }
    __syncthreads();
    {
        int nl = tid >> 2;
        int c  = (tid & 3) * 16;
        int n  = nb + nl;
        int k0 = kb + c;
        int kg0 = k0 >> 3;
        bf16x4 v0 = *(const bf16x4*)&tile[nl][c + 0];
        bf16x4 v1 = *(const bf16x4*)&tile[nl][c + 4];
        bf16x4 v2 = *(const bf16x4*)&tile[nl][c + 8];
        bf16x4 v3 = *(const bf16x4*)&tile[nl][c + 12];
        ushort_t* d0 = dst + ((size_t)(n >> 4) * (K / 8) + kg0) * 128
                           + (((n & 15) ^ (kg0 & 3)) * 8);
        ushort_t* d1 = dst + ((size_t)(n >> 4) * (K / 8) + kg0 + 1) * 128
                           + (((n & 15) ^ ((kg0 + 1) & 3)) * 8);
        *(bf16x4*)(d0 + 0) = v0;
        *(bf16x4*)(d0 + 4) = v1;
        *(bf16x4*)(d1 + 0) = v2;
        *(bf16x4*)(d1 + 4) = v3;
    }
}

// ---------------------------------------------------------------------------
// W-stationary per-task GEMM. Block = (task, col-slice, row-group):
//   - stage W slice (CF*16 cols x K) into LDS once via gld16 (linear copy)
//   - waves stream the task's H row-frags from global (task->XCD-pinned L2)
//   - no barriers after staging; per-wave frag loop with masking
// mfma(w, h): acc lane&15 = H-row, reg r -> W-col. MPI m-frags x CF col-frags
// per wave per pass; hb group-2 double-buffer; wr depth-2 LDS prefetch.
//   FINAL=0: tanh+bias -> packed bf16 H (width 1024); FINAL=1: fp32 scatter.
// ---------------------------------------------------------------------------
template<int K, int CF, int MPI, int RG, int NSLICE, int FINAL>
__global__ __launch_bounds__(512, 1) void task_gemm(
    const ushort_t* __restrict__ A,      // packed H-in, P_ROWS x K
    const ushort_t* __restrict__ Wt,     // packed+swizzled [T][N][K]
    const float* __restrict__ bias,      // [T][N]
    void* __restrict__ outp,
    const int* __restrict__ sidx,
    const int* __restrict__ pstart_g,
    const int* __restrict__ tot_g)
{
    constexpr int NS     = K / 32;
    constexpr int N      = NSLICE * CF * 16;
    constexpr int WBYTES = CF * 16 * K * 2;

    __shared__ __align__(16) char wlds[WBYTES];

    const int bid   = blockIdx.x;
    const int xcd   = bid & 7;
    const int j     = bid >> 3;
    const int task  = xcd * 2 + (j & 1);      // consistent across dispatches
    const int rest  = j >> 1;
    const int slice = rest % NSLICE;
    const int rg    = rest / NSLICE;

    const int rows   = tot_g[task];
    const int gbase  = pstart_g[task] >> 4;
    const int nfrags = (rows + 15) >> 4;

    const int tid  = threadIdx.x;
    const int lane = tid & 63;
    const int wid  = tid >> 6;
    const int q    = lane >> 4;
    const int m15  = lane & 15;

    // ---- stage W slice into LDS (byte-for-byte copy of packed image) ----
    {
        const char* ws = (const char*)(Wt + (size_t)task * N * K
                                          + (size_t)slice * (CF * 16) * K);
        #pragma unroll
        for (int r = 0; r < WBYTES / 8192; ++r)
            gld16(ws + r * 8192 + wid * 1024 + lane * 16,
                  wlds + r * 8192 + wid * 1024);
    }
    __syncthreads();

    const int n0 = slice * (CF * 16);

    for (int i0 = 0; ; ++i0) {
        const int fw0 = rg + RG * (wid * MPI + 8 * MPI * i0);
        if (fw0 >= nfrags) break;              // per-wave exit (no barriers)

        int fidx[MPI];
        const char* hp[MPI];
        #pragma unroll
        for (int mf = 0; mf < MPI; ++mf) {
            fidx[mf] = rg + RG * (wid * MPI + mf + 8 * MPI * i0);
            const int fc = fidx[mf] < nfrags ? fidx[mf] : 0;
            hp[mf] = (const char*)A + ((size_t)(gbase + fc) * (K / 8)) * 256
                   + q * 256 + m15 * 16;
        }

        f32x4 acc[MPI][CF];
        #pragma unroll
        for (int mf = 0; mf < MPI; ++mf)
            #pragma unroll
            for (int cf = 0; cf < CF; ++cf)
                acc[mf][cf] = (f32x4){0.f, 0.f, 0.f, 0.f};

        bf16x8 hb[2][2][MPI];                  // [buf][step-in-group][mf]
        #pragma unroll
        for (int s2 = 0; s2 < 2; ++s2)
            #pragma unroll
            for (int mf = 0; mf < MPI; ++mf)
                hb[0][s2][mf] = *(const bf16x8*)(hp[mf] + s2 * 1024);

        bf16x8 wr[2][CF];
        #pragma unroll
        for (int cf = 0; cf < CF; ++cf)
            wr[0][cf] = *(const bf16x8*)(wlds
                          + ((size_t)cf * (K / 8) + q) * 256
                          + ((m15 ^ (q & 3)) * 16));

        #pragma unroll
        for (int g = 0; g < NS / 2; ++g) {
            if (g + 1 < NS / 2) {              // prefetch next h group
                #pragma unroll
                for (int s2 = 0; s2 < 2; ++s2)
                    #pragma unroll
                    for (int mf = 0; mf < MPI; ++mf)
                        hb[(g + 1) & 1][s2][mf] =
                            *(const bf16x8*)(hp[mf] + ((g + 1) * 2 + s2) * 1024);
            }
            #pragma unroll
            for (int s2 = 0; s2 < 2; ++s2) {
                const int s = g * 2 + s2;
                if (s + 1 < NS) {              // prefetch next w step from LDS
                    const int kg = (s + 1) * 4 + q;
                    #pragma unroll
                    for (int cf = 0; cf < CF; ++cf)
                        wr[(s + 1) & 1][cf] = *(const bf16x8*)(wlds
                              + ((size_t)cf * (K / 8) + kg) * 256
                              + ((m15 ^ (kg & 3)) * 16));
                }
                __builtin_amdgcn_s_setprio(1);
                #pragma unroll
                for (int mf = 0; mf < MPI; ++mf)
                    #pragma unroll
                    for (int cf = 0; cf < CF; ++cf)
                        acc[mf][cf] = __builtin_amdgcn_mfma_f32_16x16x32_bf16(
                            wr[s & 1][cf], hb[g & 1][s2][mf], acc[mf][cf], 0, 0, 0);
                __builtin_amdgcn_s_setprio(0);
            }
        }

        // ---- epilogue for this pass ----
        #pragma unroll
        for (int mf = 0; mf < MPI; ++mf) {
            if (fidx[mf] >= nfrags) continue;
            const int fg = gbase + fidx[mf];
            if (!FINAL) {
                #pragma unroll
                for (int cf = 0; cf < CF; ++cf) {
                    const int n_lo = n0 + cf * 16 + q * 4;
                    const f32x4 bb = *(const f32x4*)(bias + (size_t)task * N + n_lo);
                    bf16x4 pk;
                    #pragma unroll
                    for (int r = 0; r < 4; ++r)
                        pk[r] = f2bf(fast_tanh(acc[mf][cf][r] + bb[r]));
                    char* dp = (char*)outp
                        + ((size_t)fg * 128 + (n_lo >> 3)) * 256
                        + m15 * 16 + (n_lo & 7) * 2;
                    *(bf16x4*)dp = pk;
                }
            } else {
                const int rit = fidx[mf] * 16 + m15;
                if (rit < rows) {
                    const int orow = sidx[fg * 16 + m15];
                    #pragma unroll
                    for (int cf = 0; cf < CF; ++cf) {
                        const int n_lo = n0 + cf * 16 + q * 4;
                        const f32x4 bb = *(const f32x4*)(bias + (size_t)task * N + n_lo);
                        f32x4 v;
                        #pragma unroll
                        for (int r = 0; r < 4; ++r)
                            v[r] = acc[mf][cf][r] + bb[r];
                        *(f32x4*)((float*)outp + (size_t)orow * 256 + n_lo) = v;
                    }
                }
            }
        }
    }
}

// ---------------------------------------------------------------------------
extern "C" void kernel_launch(void* const* d_in, const int* in_sizes, int n_in,
                              void* d_out, int out_size, void* d_ws, size_t ws_size,
                              hipStream_t stream)
{
    const float* x        = (const float*)d_in[0];
    const int*   task_ids = (const int*)  d_in[1];
    const float* k0       = (const float*)d_in[2];
    const float* b0       = (const float*)d_in[3];
    const float* k1       = (const float*)d_in[4];
    const float* b1       = (const float*)d_in[5];
    const float* k2       = (const float*)d_in[6];
    const float* b2       = (const float*)d_in[7];
    float* out = (float*)d_out;

    char* ws = (char*)d_ws;
    int* sidx     = (int*)ws;                 // P_ROWS ints
    int* pstart_g = sidx + P_ROWS;
    int* tot_g    = pstart_g + 16;

    size_t off = 65536;
    ushort_t* xs  = (ushort_t*)(ws + off); off += (size_t)P_ROWS * 512 * 2;
    ushort_t* H0  = (ushort_t*)(ws + off); off += (size_t)P_ROWS * 1024 * 2;
    ushort_t* H1  = (ushort_t*)(ws + off); off += (size_t)P_ROWS * 1024 * 2;
    ushort_t* Wt0 = (ushort_t*)(ws + off); off += (size_t)16 * 512 * 1024 * 2;
    ushort_t* Wt1 = (ushort_t*)(ws + off); off += (size_t)16 * 1024 * 1024 * 2;
    ushort_t* Wt2 = (ushort_t*)(ws + off); off += (size_t)16 * 1024 * 256 * 2;

    bucket_kernel<<<1, 256, 0, stream>>>(task_ids, sidx, pstart_g, tot_g);
    xconv<<<P_ROWS / 4, 256, 0, stream>>>(x, sidx, xs);
    wconv< 512, 1024><<<dim3(16,  8, 16), 256, 0, stream>>>(k0, Wt0);
    wconv<1024, 1024><<<dim3(16, 16, 16), 256, 0, stream>>>(k1, Wt1);
    wconv<1024,  256><<<dim3( 4, 16, 16), 256, 0, stream>>>(k2, Wt2);

    // L0: xs x W0 -> H0 ; 16 tasks x 16 slices = 256 blocks, W-slice 64 KB
    task_gemm< 512, 4, 4, 1, 16, 0><<<256, 512, 0, stream>>>(
        xs, Wt0, b0, H0, sidx, pstart_g, tot_g);
    // L1: H0 x W1 -> H1 ; 256 blocks, W-slice 128 KB
    task_gemm<1024, 4, 4, 1, 16, 0><<<256, 512, 0, stream>>>(
        H0, Wt1, b1, H1, sidx, pstart_g, tot_g);
    // L2: H1 x W2 -> out ; 16 tasks x 4 slices x 2 row-groups = 128 blocks
    task_gemm<1024, 4, 2, 2, 4, 1><<<128, 512, 0, stream>>>(
        H1, Wt2, b2, out, sidx, pstart_g, tot_g);
}